// Round 2
// baseline (848.603 us; speedup 1.0000x reference)
//
#include <hip/hip_runtime.h>

using short8 = __attribute__((ext_vector_type(8))) short;
using f32x16 = __attribute__((ext_vector_type(16))) float;
using us4    = __attribute__((ext_vector_type(4))) unsigned short;

#define NHID 15872
#define NCLS 32

__device__ __forceinline__ unsigned short f2bf(float f) {
  unsigned u = __builtin_bit_cast(unsigned, f);
  u += 0x7fff + ((u >> 16) & 1);          // RNE
  return (unsigned short)(u >> 16);
}
__device__ __forceinline__ float bf2f(unsigned short h) {
  return __builtin_bit_cast(float, ((unsigned)h) << 16);
}

// ---------------- kernel 0: x fp32 -> bf16 ----------------
__global__ void cvt_x(const float* __restrict__ x, unsigned short* __restrict__ xb) {
  int i = (blockIdx.x * 256 + threadIdx.x) * 4;
  float4 v = *reinterpret_cast<const float4*>(x + i);
  us4 o;
  o[0] = f2bf(v.x); o[1] = f2bf(v.y); o[2] = f2bf(v.z); o[3] = f2bf(v.w);
  *reinterpret_cast<us4*>(xb + i) = o;
}

// ---------------- main GEMM: C_bf16[256][15872] = relu(A_bf16 @ B_f32 + bias) ----------------
// grid = 248 (N tiles of 64), block = 512 (8 waves: 4M x 2N), BK=64
__global__ __launch_bounds__(512, 2)
void gemm_rc(const unsigned short* __restrict__ A, int lda, int K,
             const float* __restrict__ B, const float* __restrict__ bias,
             unsigned short* __restrict__ C)
{
  __shared__ short Blds[2][64 * 64];   // [buf][col][k] bf16, 16B-chunk swizzled
  const int tid  = threadIdx.x;
  const int n0   = blockIdx.x * 64;
  const int lane = tid & 63;
  const int w    = tid >> 6;
  const int wm   = w >> 1;     // 0..3 -> 64 rows each
  const int wn   = w & 1;      // 0..1 -> 32 cols each
  const int l31  = lane & 31;
  const int hi   = lane >> 5;

  f32x16 acc0 = {0.f,0.f,0.f,0.f,0.f,0.f,0.f,0.f,0.f,0.f,0.f,0.f,0.f,0.f,0.f,0.f};
  f32x16 acc1 = acc0;

  // staging assignment: thread -> (col sc, k-strip sk0..sk0+7)
  const int sc  = tid & 63;
  const int sk0 = (tid >> 6) * 8;
  const int sldsoff = sc * 64 + (((sk0 >> 3) ^ (sc & 7)) * 8);
  const float* bbase = B + (size_t)sk0 * NHID + n0 + sc;

  float br[8];
  const int NT = K / 64;

  // prologue: stage tile 0
  {
    const float* p = bbase;
#pragma unroll
    for (int i = 0; i < 8; ++i) br[i] = p[(size_t)i * NHID];
    short8 hv;
#pragma unroll
    for (int i = 0; i < 8; ++i) hv[i] = (short)f2bf(br[i]);
    *reinterpret_cast<short8*>(&Blds[0][sldsoff]) = hv;
  }
  __syncthreads();

  const unsigned short* abase = A + (size_t)(wm * 64 + l31) * lda + hi * 8;
  const int bcol = wn * 32 + l31;
  int cur = 0;

  for (int t = 0; t < NT; ++t) {
    // issue next tile's global loads (overlap with compute below)
    if (t + 1 < NT) {
      const float* p = bbase + (size_t)(t + 1) * 64 * NHID;
#pragma unroll
      for (int i = 0; i < 8; ++i) br[i] = p[(size_t)i * NHID];
    }
    // A fragments direct from global (L1/L2-resident operand)
    short8 a0[4], a1[4];
#pragma unroll
    for (int kk = 0; kk < 4; ++kk) {
      size_t ko = (size_t)t * 64 + kk * 16;
      a0[kk] = *reinterpret_cast<const short8*>(abase + ko);
      a1[kk] = *reinterpret_cast<const short8*>(abase + (size_t)32 * lda + ko);
    }
    // B fragments from LDS + MFMA
#pragma unroll
    for (int kk = 0; kk < 4; ++kk) {
      int chunk = kk * 2 + hi;
      short8 bfr = *reinterpret_cast<const short8*>(
          &Blds[cur][bcol * 64 + ((chunk ^ (bcol & 7)) * 8)]);
      acc0 = __builtin_amdgcn_mfma_f32_32x32x16_bf16(a0[kk], bfr, acc0, 0, 0, 0);
      acc1 = __builtin_amdgcn_mfma_f32_32x32x16_bf16(a1[kk], bfr, acc1, 0, 0, 0);
    }
    // write next tile into the other LDS buffer
    if (t + 1 < NT) {
      short8 hv;
#pragma unroll
      for (int i = 0; i < 8; ++i) hv[i] = (short)f2bf(br[i]);
      *reinterpret_cast<short8*>(&Blds[cur ^ 1][sldsoff]) = hv;
    }
    __syncthreads();
    cur ^= 1;
  }

  // epilogue: bias + relu + bf16 store
  const int col = n0 + wn * 32 + l31;
  const float bv = bias[col];
#pragma unroll
  for (int reg = 0; reg < 16; ++reg) {
    int rowoff = (reg & 3) + 8 * (reg >> 2) + 4 * hi;
    {
      int row = wm * 64 + rowoff;
      float v = acc0[reg] + bv; v = v > 0.f ? v : 0.f;
      C[(size_t)row * NHID + col] = f2bf(v);
    }
    {
      int row = wm * 64 + 32 + rowoff;
      float v = acc1[reg] + bv; v = v > 0.f ? v : 0.f;
      C[(size_t)row * NHID + col] = f2bf(v);
    }
  }
}

// ---------------- kernel: fold Wout [15872][992] -> Wv [15872][32] ----------------
__global__ void wv_fold(const float* __restrict__ Wout, float* __restrict__ Wv) {
  int g = blockIdx.x * 256 + threadIdx.x;   // < 15872*32
  int k = g >> 5, c = g & 31;
  const float* row = Wout + (size_t)k * 992;
  float s = 0.f;
#pragma unroll
  for (int o = 0; o < 32; ++o) {
    if (o == c) continue;
    int i = c < o ? c : o;
    int j = c < o ? o : c;
    int p = 31 * i - (i * (i - 1)) / 2 + (j - i - 1);
    s += row[2 * p + (c > o ? 1 : 0)];
  }
  Wv[g] = s;
}

// ---------------- kernel: votes partial = h2 @ Wv, K-split 32 ----------------
__global__ void votes_partial(const unsigned short* __restrict__ h2,
                              const float* __restrict__ Wv,
                              float* __restrict__ part) {
  int bm = blockIdx.x >> 5;        // 0..31 -> 8 rows each
  int ks = blockIdx.x & 31;        // K split
  int r  = bm * 8 + (threadIdx.x >> 5);
  int c  = threadIdx.x & 31;
  const unsigned short* hrow = h2 + (size_t)r * NHID + ks * 496;
  const float* wp = Wv + (size_t)(ks * 496) * 32 + c;
  float s = 0.f;
#pragma unroll 4
  for (int k = 0; k < 496; ++k) {
    s += bf2f(hrow[k]) * wp[(size_t)k * 32];
  }
  part[(size_t)(ks * 256 + r) * 32 + c] = s;
}

// ---------------- kernel: reduce partials + bias-fold ----------------
__global__ void votes_reduce(const float* __restrict__ part,
                             const float* __restrict__ bout,
                             float* __restrict__ out) {
  int g = blockIdx.x * 256 + threadIdx.x;  // < 8192
  int c = g & 31;
  float s = 0.f;
#pragma unroll
  for (int ks = 0; ks < 32; ++ks) s += part[(size_t)ks * 8192 + g];
  float bv = 0.f;
#pragma unroll
  for (int o = 0; o < 32; ++o) {
    if (o == c) continue;
    int i = c < o ? c : o;
    int j = c < o ? o : c;
    int p = 31 * i - (i * (i - 1)) / 2 + (j - i - 1);
    bv += bout[2 * p + (c > o ? 1 : 0)];
  }
  out[g] = s + bv;
}

extern "C" void kernel_launch(void* const* d_in, const int* in_sizes, int n_in,
                              void* d_out, int out_size, void* d_ws, size_t ws_size,
                              hipStream_t stream) {
  const float* x    = (const float*)d_in[0];
  const float* W1   = (const float*)d_in[1];
  const float* b1   = (const float*)d_in[2];
  const float* W2   = (const float*)d_in[3];
  const float* b2   = (const float*)d_in[4];
  const float* Wout = (const float*)d_in[5];
  const float* bout = (const float*)d_in[6];
  float* out = (float*)d_out;

  char* ws = (char*)d_ws;
  unsigned short* xb = (unsigned short*)(ws);                       // 256*512*2   = 262144
  unsigned short* h1 = (unsigned short*)(ws + 262144);              // 256*15872*2 = 8126464
  unsigned short* h2 = (unsigned short*)(ws + 8388608);             // 8126464
  float*          Wv = (float*)(ws + 16515072);                     // 15872*32*4  = 2031616
  float*        part = (float*)(ws + 18546688);                     // 32*256*32*4 = 1048576

  hipLaunchKernelGGL(cvt_x,         dim3(128),  dim3(256), 0, stream, x, xb);
  hipLaunchKernelGGL(gemm_rc,       dim3(248),  dim3(512), 0, stream, xb, 512, 512, W1, b1, h1);
  hipLaunchKernelGGL(gemm_rc,       dim3(248),  dim3(512), 0, stream, h1, NHID, NHID, W2, b2, h2);
  hipLaunchKernelGGL(wv_fold,       dim3(1984), dim3(256), 0, stream, Wout, Wv);
  hipLaunchKernelGGL(votes_partial, dim3(1024), dim3(256), 0, stream, h2, Wv, part);
  hipLaunchKernelGGL(votes_reduce,  dim3(32),   dim3(256), 0, stream, part, bout, out);
}